// Round 4
// baseline (708.074 us; speedup 1.0000x reference)
//
#include <hip/hip_runtime.h>

#define SPATIAL 16384
#define BATCH 8
#define CDIM 384
#define QVDIM 768
#define PDIM 192
#define NHEADS 8
#define HC 48

typedef __attribute__((ext_vector_type(8))) short short8;
typedef __attribute__((ext_vector_type(4))) float f32x4;
typedef __attribute__((ext_vector_type(4))) int i32x4;

__device__ __forceinline__ unsigned short f2bf(float f) {
  union { float f; unsigned u; } v; v.f = f;
  unsigned r = v.u + 0x7fffu + ((v.u >> 16) & 1u);
  return (unsigned short)(r >> 16);
}
__device__ __forceinline__ float bf2f(unsigned short h) {
  union { unsigned u; float f; } v; v.u = ((unsigned)h) << 16;
  return v.f;
}

// async global->LDS, 16B per lane; LDS dest is wave-uniform base + lane*16
__device__ __forceinline__ void gload16(const unsigned short* g, unsigned short* lds) {
  __builtin_amdgcn_global_load_lds(
      (const __attribute__((address_space(1))) void*)g,
      (__attribute__((address_space(3))) void*)lds,
      16, 0, 0);
}

// ---------------- weight fp32 -> bf16 ----------------
__global__ void k_w2bf(const float* __restrict__ in, unsigned short* __restrict__ out, int n) {
  int i = blockIdx.x * 256 + threadIdx.x;
  if (i < n) out[i] = f2bf(in[i]);
}

// ---------------- transpose fp32 [B][C][S] -> bf16 [B][S][C], 64x64 tiles ----------------
__global__ __launch_bounds__(256)
void k_transpose(const float* __restrict__ in, unsigned short* __restrict__ out, int C) {
  __shared__ float tile[64][65];
  int bid = blockIdx.x;
  int st = bid % (SPATIAL / 64); bid /= (SPATIAL / 64);
  int ct = bid % (C / 64); int b = bid / (C / 64);
  int t = threadIdx.x;
  const float* ip = in + ((size_t)b * C + (size_t)ct * 64) * SPATIAL + (size_t)st * 64;
  int fx = t & 15, fy = t >> 4;
#pragma unroll
  for (int i = 0; i < 4; i++) {
    int r = fy + i * 16;
    f32x4 v = *(const f32x4*)(ip + (size_t)r * SPATIAL + fx * 4);
    tile[r][fx * 4 + 0] = v[0];
    tile[r][fx * 4 + 1] = v[1];
    tile[r][fx * 4 + 2] = v[2];
    tile[r][fx * 4 + 3] = v[3];
  }
  __syncthreads();
  unsigned short* op = out + ((size_t)b * SPATIAL + (size_t)st * 64) * C + (size_t)ct * 64;
  int cg = t & 7, sr = t >> 3;
#pragma unroll
  for (int i = 0; i < 2; i++) {
    int s = sr + i * 32;
    short8 o;
#pragma unroll
    for (int j = 0; j < 8; j++) o[j] = (short)f2bf(tile[cg * 8 + j][s]);
    *(short8*)(op + (size_t)s * C + cg * 8) = o;
  }
}

// ---------------- GEMM: C[b][M][S] = A[M][K] @ B[b][S][K]^T ----------------
// Double-buffered 2-phase pipeline, global_load_lds staging with source-side XOR
// swizzle, mb-innermost + XCD chunk swizzle. fp32 output path uses LDS-bounce
// coalesced epilogue (dwordx4 stores).
template<bool OUT_BF16>
__global__ __launch_bounds__(256)
void k_gemm(const unsigned short* __restrict__ A, const unsigned short* __restrict__ B,
            void* __restrict__ Cv, int M, int K, long strideA)
{
  int nwg = gridDim.x;                                // always % 8 == 0 here
  int bid = (blockIdx.x & 7) * (nwg >> 3) + (blockIdx.x >> 3);
  int mt = M >> 7;
  int mb = bid % mt; bid /= mt;
  int nb = bid & 127; int b = bid >> 7;

  const unsigned short* Ab = A + (size_t)b * strideA + (size_t)mb * 128 * K;
  const unsigned short* Bb = B + ((size_t)b * SPATIAL + (size_t)nb * 128) * K;

  __shared__ __align__(16) char smem[OUT_BF16 ? 32768 : 33792];
  unsigned short* lA = (unsigned short*)smem;          // [2][4096]
  unsigned short* lB = lA + 8192;                      // [2][4096]

  int t = threadIdx.x;
  int lane = t & 63;
  int w = t >> 6;
  int wm = (w >> 1) * 64, wn = (w & 1) * 64;
  int lr = lane & 15, lg = lane >> 4;

  f32x4 acc[4][4];
#pragma unroll
  for (int i = 0; i < 4; i++)
#pragma unroll
    for (int j = 0; j < 4; j++)
      acc[i][j] = (f32x4){0.f, 0.f, 0.f, 0.f};

  int r0 = t >> 2, kc = t & 3;
  int xorc = (kc ^ ((r0 >> 1) & 3)) * 8;              // (r0+64)>>1 & 3 == (r0>>1)&3
  const unsigned short* gA0 = Ab + (size_t)r0 * K + xorc;
  const unsigned short* gA1 = Ab + (size_t)(r0 + 64) * K + xorc;
  const unsigned short* gB0 = Bb + (size_t)r0 * K + xorc;
  const unsigned short* gB1 = Bb + (size_t)(r0 + 64) * K + xorc;
  int ls0 = w * 512;                                  // element offsets in each buffer
  int ls1 = 2048 + w * 512;

  int nt = K >> 5;
  gload16(gA0, &lA[ls0]);
  gload16(gA1, &lA[ls1]);
  gload16(gB0, &lB[ls0]);
  gload16(gB1, &lB[ls1]);

  int colr = (lg ^ ((lr >> 1) & 3)) * 8;

  for (int tile = 0; tile < nt; ++tile) {
    int cur = tile & 1;
    if (tile + 1 < nt) {
      int k0 = (tile + 1) << 5;
      int nxt = (cur ^ 1) * 4096;
      gload16(gA0 + k0, &lA[nxt + ls0]);
      gload16(gA1 + k0, &lA[nxt + ls1]);
      gload16(gB0 + k0, &lB[nxt + ls0]);
      gload16(gB1 + k0, &lB[nxt + ls1]);
      asm volatile("s_waitcnt vmcnt(4)" ::: "memory");
    } else {
      asm volatile("s_waitcnt vmcnt(0)" ::: "memory");
    }
    __builtin_amdgcn_s_barrier();
    __builtin_amdgcn_sched_barrier(0);

    int cb = cur * 4096;
    short8 af[4], bfr[4];
#pragma unroll
    for (int mi = 0; mi < 4; mi++)
      af[mi] = *(const short8*)(&lA[cb + (wm + mi * 16 + lr) * 32 + colr]);
#pragma unroll
    for (int ni = 0; ni < 4; ni++)
      bfr[ni] = *(const short8*)(&lB[cb + (wn + ni * 16 + lr) * 32 + colr]);
#pragma unroll
    for (int mi = 0; mi < 4; mi++)
#pragma unroll
      for (int ni = 0; ni < 4; ni++)
        acc[mi][ni] = __builtin_amdgcn_mfma_f32_16x16x32_bf16(af[mi], bfr[ni], acc[mi][ni], 0, 0, 0);

    __builtin_amdgcn_sched_barrier(0);
    __builtin_amdgcn_s_barrier();
  }

  if (OUT_BF16) {
    size_t rbase = (size_t)mb * 128 + wm + lg * 4;
    size_t cbase = (size_t)nb * 128 + wn + lr;
    unsigned short* C = (unsigned short*)Cv + (size_t)b * M * SPATIAL;
#pragma unroll
    for (int mi = 0; mi < 4; mi++)
#pragma unroll
      for (int ni = 0; ni < 4; ni++) {
        size_t r = rbase + mi * 16;
        size_t c = cbase + ni * 16;
#pragma unroll
        for (int j = 0; j < 4; j++)
          C[(r + j) * SPATIAL + c] = f2bf(acc[mi][ni][j]);
      }
  } else {
    // LDS-bounce coalesced fp32 epilogue, two 64-row halves
    float* lC = (float*)smem;                         // [64][132]
    float* Cg = (float*)Cv + (size_t)b * M * SPATIAL;
#pragma unroll
    for (int half = 0; half < 2; ++half) {
      __syncthreads();
      if (wm == half * 64) {
#pragma unroll
        for (int mi = 0; mi < 4; mi++)
#pragma unroll
          for (int ni = 0; ni < 4; ni++) {
            int rl = mi * 16 + lg * 4;
            int c = wn + ni * 16 + lr;
#pragma unroll
            for (int j = 0; j < 4; j++)
              lC[(rl + j) * 132 + c] = acc[mi][ni][j];
          }
      }
      __syncthreads();
      int rl = t >> 2, c4 = (t & 3) * 4;
      size_t rg = (size_t)mb * 128 + half * 64 + rl;
#pragma unroll
      for (int i = 0; i < 8; i++) {
        f32x4 v = *(const f32x4*)(&lC[rl * 132 + i * 16 + c4]);
        *(f32x4*)(Cg + rg * SPATIAL + (size_t)nb * 128 + i * 16 + c4) = v;
      }
    }
  }
}

// ---------------- depthwise 3x3 on v-half of qv, vectorized, transposed out vT [B][S][384] ----------------
__global__ __launch_bounds__(256)
void k_dwconv_t(const unsigned short* __restrict__ qv, const float* __restrict__ wdw,
                unsigned short* __restrict__ vT)
{
  __shared__ float tile[128][17];                     // [x][c-local]
  int bid = blockIdx.x;
  int y = bid & 127; bid >>= 7;
  int ct = bid % 24; int b = bid / 24;                // 24 tiles of 16 channels
  int t = threadIdx.x;
  int ci = t >> 4, xs = (t & 15) * 8;
  int c = CDIM + ct * 16 + ci;
  const unsigned short* ip = qv + ((size_t)b * QVDIM + c) * SPATIAL;
  const float* wp = wdw + (size_t)c * 9;
  float wr[9];
#pragma unroll
  for (int i = 0; i < 9; i++) wr[i] = wp[i];

  float acc[8];
#pragma unroll
  for (int j = 0; j < 8; j++) acc[j] = 0.f;

  auto row = [&](int yy, float wa, float wb, float wc) {
    if ((unsigned)yy >= 128u) return;
    const unsigned short* rp = ip + yy * 128 + xs;
    short8 cv = *(const short8*)rp;
    float cf[8];
#pragma unroll
    for (int j = 0; j < 8; j++) cf[j] = bf2f((unsigned short)cv[j]);
    float lf = (xs > 0) ? bf2f(rp[-1]) : 0.f;
    float rt = (xs < 120) ? bf2f(rp[8]) : 0.f;
    acc[0] += wa * lf + wb * cf[0] + wc * cf[1];
#pragma unroll
    for (int j = 1; j < 7; j++) acc[j] += wa * cf[j - 1] + wb * cf[j] + wc * cf[j + 1];
    acc[7] += wa * cf[6] + wb * cf[7] + wc * rt;
  };
  row(y - 1, wr[0], wr[1], wr[2]);
  row(y,     wr[3], wr[4], wr[5]);
  row(y + 1, wr[6], wr[7], wr[8]);

#pragma unroll
  for (int j = 0; j < 8; j++) tile[xs + j][ci] = acc[j];
  __syncthreads();

  int xw = t >> 1, cg = t & 1;
  short8 o;
#pragma unroll
  for (int j = 0; j < 8; j++) o[j] = (short)f2bf(tile[xw][cg * 8 + j]);
  *(short8*)(vT + ((size_t)b * SPATIAL + (size_t)y * 128 + xw) * CDIM + ct * 16 + cg * 8) = o;
}

// ---------------- FUSED: dwconv(q) + dwconv(k) + norms + logits ----------------
// One block = (b, h, 2-row spatial strip). Conv 48 q-chans + 48 k-chans into
// swizzled LDS tiles [ks][48][32], accumulate ||.||^2 atomics, then MFMA the
// 3x3 48x48 logit frags (frag-split across waves) and atomically add into raw.
__global__ __launch_bounds__(256)
void k_fused(const unsigned short* __restrict__ qv, const unsigned short* __restrict__ kpre,
             const float* __restrict__ w_qvdw, const float* __restrict__ w_kdw,
             float* __restrict__ n2q, float* __restrict__ n2k, float* __restrict__ raw)
{
  __shared__ unsigned short lds[24576];               // q: [0,12288), k: [12288,24576)
  int bid = blockIdx.x;
  int st = bid & 63; int h = (bid >> 6) & 7; int b = bid >> 9;
  int y0 = st * 2;
  int t = threadIdx.x;

  int px = (t & 31) * 8;
  int y = y0 + (px >> 7);
  int x = px & 127;

#pragma unroll
  for (int tens = 0; tens < 2; ++tens) {
    const unsigned short* src;
    const float* wsrc;
    float* nrm;
    unsigned short* dst;
    size_t cstride;
    if (tens == 0) { src = qv;   wsrc = w_qvdw; nrm = n2q; dst = &lds[0];     cstride = QVDIM; }
    else           { src = kpre; wsrc = w_kdw;  nrm = n2k; dst = &lds[12288]; cstride = CDIM;  }
#pragma unroll
    for (int p = 0; p < 6; ++p) {
      int cl = p * 8 + (t >> 5);
      int chan = h * HC + cl;
      const unsigned short* ip = src + ((size_t)b * cstride + chan) * SPATIAL;
      const float* wp = wsrc + (size_t)chan * 9;
      float wr[9];
#pragma unroll
      for (int i = 0; i < 9; i++) wr[i] = wp[i];
      float acc[8];
#pragma unroll
      for (int j = 0; j < 8; j++) acc[j] = 0.f;
      auto row = [&](int yy, float wa, float wb, float wc) {
        if ((unsigned)yy >= 128u) return;
        const unsigned short* rp = ip + yy * 128 + x;
        short8 cv = *(const short8*)rp;
        float cf[8];
#pragma unroll
        for (int j = 0; j < 8; j++) cf[j] = bf2f((unsigned short)cv[j]);
        float lf = (x > 0) ? bf2f(rp[-1]) : 0.f;
        float rt = (x < 120) ? bf2f(rp[8]) : 0.f;
        acc[0] += wa * lf + wb * cf[0] + wc * cf[1];
#pragma unroll
        for (int j = 1; j < 7; j++) acc[j] += wa * cf[j - 1] + wb * cf[j] + wc * cf[j + 1];
        acc[7] += wa * cf[6] + wb * cf[7] + wc * rt;
      };
      row(y - 1, wr[0], wr[1], wr[2]);
      row(y,     wr[3], wr[4], wr[5]);
      row(y + 1, wr[6], wr[7], wr[8]);

      short8 o;
      float sq = 0.f;
#pragma unroll
      for (int j = 0; j < 8; j++) {
        o[j] = (short)f2bf(acc[j]);
        float v = bf2f((unsigned short)o[j]);
        sq += v * v;
      }
      // swizzled LDS tile write: [ks=px>>5][48][32], unit xor (cl>>1)&3
      int addr = ((px >> 5) * 48 + cl) * 32 + ((((px & 31) >> 3) ^ ((cl >> 1) & 3)) * 8);
      *(short8*)(dst + addr) = o;

#pragma unroll
      for (int off = 16; off > 0; off >>= 1) sq += __shfl_xor(sq, off, 64);
      if ((t & 31) == 0) atomicAdd(&nrm[b * CDIM + h * HC + cl], sq);
    }
  }
  __syncthreads();

  // logits: frag (ci,di) f=ci*3+di assigned to wave f&3
  int lane = t & 63, wv = t >> 6;
  int lr = lane & 15, lg = lane >> 4;
  int nf = (wv == 0) ? 3 : 2;
  f32x4 acc[3];
  int cis[3], dis[3];
#pragma unroll
  for (int i = 0; i < 3; i++) {
    int f = wv + i * 4;
    cis[i] = f / 3; dis[i] = f % 3;
    acc[i] = (f32x4){0.f, 0.f, 0.f, 0.f};
  }
  for (int ks = 0; ks < 8; ++ks) {
#pragma unroll
    for (int i = 0; i < 3; i++) {
      if (i >= nf) break;
      int cq = cis[i] * 16 + lr;
      int ck = dis[i] * 16 + lr;
      short8 af = *(const short8*)(&lds[(ks * 48 + cq) * 32 + (lg ^ ((cq >> 1) & 3)) * 8]);
      short8 bf = *(const short8*)(&lds[12288 + (ks * 48 + ck) * 32 + (lg ^ ((ck >> 1) & 3)) * 8]);
      acc[i] = __builtin_amdgcn_mfma_f32_16x16x32_bf16(af, bf, acc[i], 0, 0, 0);
    }
  }
  float* rp = raw + ((size_t)(b * NHEADS + h)) * HC * HC;
#pragma unroll
  for (int i = 0; i < 3; i++) {
    if (i >= nf) break;
#pragma unroll
    for (int j = 0; j < 4; j++)
      atomicAdd(&rp[(cis[i] * 16 + lg * 4 + j) * HC + dis[i] * 16 + lr], acc[i][j]);
  }
}

// ---------------- scale by norms+temperature, softmax over d ----------------
__global__ void k_softmax(const float* __restrict__ raw, const float* __restrict__ n2q,
                          const float* __restrict__ n2k, const float* __restrict__ temp,
                          float* __restrict__ attn)
{
  int h = blockIdx.x & 7, b = blockIdx.x >> 3;
  int c = threadIdx.x;
  if (c >= HC) return;
  float tp = temp[h];
  float qn = fmaxf(sqrtf(n2q[b * CDIM + h * HC + c]), 1e-12f);
  const float* rp = raw + ((size_t)(b * NHEADS + h) * HC + c) * HC;
  float vals[HC];
  float mx = -1e30f;
#pragma unroll
  for (int d = 0; d < HC; d++) {
    float kn = fmaxf(sqrtf(n2k[b * CDIM + h * HC + d]), 1e-12f);
    float v = rp[d] * tp / (qn * kn);
    vals[d] = v;
    mx = fmaxf(mx, v);
  }
  float sum = 0.f;
#pragma unroll
  for (int d = 0; d < HC; d++) { vals[d] = expf(vals[d] - mx); sum += vals[d]; }
  float inv = 1.f / sum;
  float* ap = attn + ((size_t)(b * NHEADS + h) * HC + c) * HC;
#pragma unroll
  for (int d = 0; d < HC; d++) ap[d] = vals[d] * inv;
}

// ---------------- M[b][o][h*48+d] = sum_c wproj[o][h*48+c] * attn[b][h][c][d] ----------------
__global__ void k_mbuild(const float* __restrict__ attn, const float* __restrict__ wproj,
                         unsigned short* __restrict__ Mb)
{
  int o = blockIdx.x % CDIM, b = blockIdx.x / CDIM;
  int j = threadIdx.x;           // 0..383
  int h = j / HC, d = j % HC;
  const float* wp = wproj + (size_t)o * CDIM + h * HC;
  const float* ap = attn + (size_t)(b * NHEADS + h) * HC * HC + d;
  float s = 0.f;
#pragma unroll
  for (int cp = 0; cp < HC; cp++) s += wp[cp] * ap[cp * HC];
  Mb[((size_t)b * CDIM + o) * CDIM + j] = f2bf(s);
}

// ---------------- workspace layout (bytes) ----------------
static const size_t OFF_QV   = 0;            // qv bf16 [B][768][S]
static const size_t OFF_XT   = 201326592;    // xT bf16 [B][S][384]
static const size_t OFF_DET  = 301989888;    // deT bf16 [B][S][192]
static const size_t OFF_VT   = 301989888;    // vT bf16 [B][S][384] (alias over dead deT)
static const size_t OFF_KPRE = 402653184;    // k_pre bf16 [B][384][S]
static const size_t OFF_WQVB = 503316480;
static const size_t OFF_WKB  = 503906304;
static const size_t OFF_N2Q  = 504053760;
static const size_t OFF_N2K  = 504066048;
static const size_t OFF_RAW  = 504078336;
static const size_t OFF_ATTN = 504668160;
static const size_t OFF_MB   = 505257984;    // -> end ~484 MB

extern "C" void kernel_launch(void* const* d_in, const int* in_sizes, int n_in,
                              void* d_out, int out_size, void* d_ws, size_t ws_size,
                              hipStream_t stream) {
  const float* x      = (const float*)d_in[0];
  const float* de     = (const float*)d_in[1];
  const float* w_qv   = (const float*)d_in[2];
  const float* w_qvdw = (const float*)d_in[3];
  const float* w_k    = (const float*)d_in[4];
  const float* w_kdw  = (const float*)d_in[5];
  const float* w_proj = (const float*)d_in[6];
  const float* temp   = (const float*)d_in[7];

  char* ws = (char*)d_ws;
  unsigned short* qv    = (unsigned short*)(ws + OFF_QV);
  unsigned short* xT    = (unsigned short*)(ws + OFF_XT);
  unsigned short* deT   = (unsigned short*)(ws + OFF_DET);
  unsigned short* vT    = (unsigned short*)(ws + OFF_VT);
  unsigned short* kpre  = (unsigned short*)(ws + OFF_KPRE);
  unsigned short* wqvb  = (unsigned short*)(ws + OFF_WQVB);
  unsigned short* wkb   = (unsigned short*)(ws + OFF_WKB);
  float* n2q  = (float*)(ws + OFF_N2Q);
  float* n2k  = (float*)(ws + OFF_N2K);
  float* raw  = (float*)(ws + OFF_RAW);
  float* attn = (float*)(ws + OFF_ATTN);
  unsigned short* Mb = (unsigned short*)(ws + OFF_MB);

  hipMemsetAsync(ws + OFF_N2Q, 0, 12288 + 12288 + 589824, stream);

  k_w2bf<<<dim3((QVDIM * CDIM + 255) / 256), dim3(256), 0, stream>>>(w_qv, wqvb, QVDIM * CDIM);
  k_w2bf<<<dim3((CDIM * PDIM + 255) / 256), dim3(256), 0, stream>>>(w_k, wkb, CDIM * PDIM);

  k_transpose<<<dim3(BATCH * (CDIM / 64) * (SPATIAL / 64)), dim3(256), 0, stream>>>(x, xT, CDIM);
  k_transpose<<<dim3(BATCH * (PDIM / 64) * (SPATIAL / 64)), dim3(256), 0, stream>>>(de, deT, PDIM);

  // GEMM1: qv = w_qv @ x   (M=768, K=384); GEMM1b: k_pre = w_k @ de (M=384, K=192)
  k_gemm<true><<<dim3(BATCH * (QVDIM / 128) * (SPATIAL / 128)), dim3(256), 0, stream>>>(
      wqvb, xT, (void*)qv, QVDIM, CDIM, 0L);
  k_gemm<true><<<dim3(BATCH * (CDIM / 128) * (SPATIAL / 128)), dim3(256), 0, stream>>>(
      wkb, deT, (void*)kpre, CDIM, PDIM, 0L);

  // v depthwise conv -> transposed vT (B-operand of GEMM2)
  k_dwconv_t<<<dim3(BATCH * 24 * 128), dim3(256), 0, stream>>>(qv, w_qvdw, vT);

  // fused dwconv(q)+dwconv(k)+norms+logits
  k_fused<<<dim3(BATCH * NHEADS * 64), dim3(256), 0, stream>>>(
      qv, kpre, w_qvdw, w_kdw, n2q, n2k, raw);

  k_softmax<<<dim3(BATCH * NHEADS), dim3(64), 0, stream>>>(raw, n2q, n2k, temp, attn);
  k_mbuild<<<dim3(BATCH * CDIM), dim3(CDIM), 0, stream>>>(attn, w_proj, Mb);

  // GEMM2: out = M[b] @ v  (M=384, K=384), fp32 output via coalesced LDS-bounce epilogue
  k_gemm<false><<<dim3(BATCH * (CDIM / 128) * (SPATIAL / 128)), dim3(256), 0, stream>>>(
      Mb, vT, d_out, CDIM, CDIM, (long)(CDIM * CDIM));
}

// Round 5
// 680.787 us; speedup vs baseline: 1.0401x; 1.0401x over previous
//
#include <hip/hip_runtime.h>

#define SPATIAL 16384
#define BATCH 8
#define CDIM 384
#define QVDIM 768
#define PDIM 192
#define NHEADS 8
#define HC 48

typedef __attribute__((ext_vector_type(8))) short short8;
typedef __attribute__((ext_vector_type(4))) float f32x4;
typedef __attribute__((ext_vector_type(4))) int i32x4;

__device__ __forceinline__ unsigned short f2bf(float f) {
  union { float f; unsigned u; } v; v.f = f;
  unsigned r = v.u + 0x7fffu + ((v.u >> 16) & 1u);
  return (unsigned short)(r >> 16);
}
__device__ __forceinline__ float bf2f(unsigned short h) {
  union { unsigned u; float f; } v; v.u = ((unsigned)h) << 16;
  return v.f;
}

// async global->LDS, 16B per lane; LDS dest is wave-uniform base + lane*16
__device__ __forceinline__ void gload16(const unsigned short* g, unsigned short* lds) {
  __builtin_amdgcn_global_load_lds(
      (const __attribute__((address_space(1))) void*)g,
      (__attribute__((address_space(3))) void*)lds,
      16, 0, 0);
}

// ---------------- weight fp32 -> bf16 ----------------
__global__ void k_w2bf(const float* __restrict__ in, unsigned short* __restrict__ out, int n) {
  int i = blockIdx.x * 256 + threadIdx.x;
  if (i < n) out[i] = f2bf(in[i]);
}

// ---------------- transpose fp32 [B][C][S] -> bf16 [B][S][C], 64x64 tiles ----------------
__global__ __launch_bounds__(256)
void k_transpose(const float* __restrict__ in, unsigned short* __restrict__ out, int C) {
  __shared__ float tile[64][65];
  int bid = blockIdx.x;
  int st = bid % (SPATIAL / 64); bid /= (SPATIAL / 64);
  int ct = bid % (C / 64); int b = bid / (C / 64);
  int t = threadIdx.x;
  const float* ip = in + ((size_t)b * C + (size_t)ct * 64) * SPATIAL + (size_t)st * 64;
  int fx = t & 15, fy = t >> 4;
#pragma unroll
  for (int i = 0; i < 4; i++) {
    int r = fy + i * 16;
    f32x4 v = *(const f32x4*)(ip + (size_t)r * SPATIAL + fx * 4);
    tile[r][fx * 4 + 0] = v[0];
    tile[r][fx * 4 + 1] = v[1];
    tile[r][fx * 4 + 2] = v[2];
    tile[r][fx * 4 + 3] = v[3];
  }
  __syncthreads();
  unsigned short* op = out + ((size_t)b * SPATIAL + (size_t)st * 64) * C + (size_t)ct * 64;
  int cg = t & 7, sr = t >> 3;
#pragma unroll
  for (int i = 0; i < 2; i++) {
    int s = sr + i * 32;
    short8 o;
#pragma unroll
    for (int j = 0; j < 8; j++) o[j] = (short)f2bf(tile[cg * 8 + j][s]);
    *(short8*)(op + (size_t)s * C + cg * 8) = o;
  }
}

// ---------------- GEMM: C[b][M][S] = A[M][K] @ B[b][S][K]^T ----------------
// Prefetch-depth-2 pipeline: 3 LDS buffers, steady-state s_waitcnt vmcnt(8)
// (two tiles always in flight, never drained in the main loop), tail 4 -> 0.
// global_load_lds staging with source-side XOR swizzle, mb-innermost + XCD
// chunk swizzle. fp32 output uses LDS-bounce coalesced epilogue.
template<bool OUT_BF16>
__global__ __launch_bounds__(256)
void k_gemm(const unsigned short* __restrict__ A, const unsigned short* __restrict__ B,
            void* __restrict__ Cv, int M, int K, long strideA)
{
  int nwg = gridDim.x;                                // always % 8 == 0 here
  int bid = (blockIdx.x & 7) * (nwg >> 3) + (blockIdx.x >> 3);
  int mt = M >> 7;
  int mb = bid % mt; bid /= mt;
  int nb = bid & 127; int b = bid >> 7;

  const unsigned short* Ab = A + (size_t)b * strideA + (size_t)mb * 128 * K;
  const unsigned short* Bb = B + ((size_t)b * SPATIAL + (size_t)nb * 128) * K;

  __shared__ __align__(16) char smem[49152];
  unsigned short* lA = (unsigned short*)smem;          // 3 x 4096 elems
  unsigned short* lB = lA + 12288;                     // 3 x 4096 elems

  int t = threadIdx.x;
  int lane = t & 63;
  int w = t >> 6;
  int wm = (w >> 1) * 64, wn = (w & 1) * 64;
  int lr = lane & 15, lg = lane >> 4;

  f32x4 acc[4][4];
#pragma unroll
  for (int i = 0; i < 4; i++)
#pragma unroll
    for (int j = 0; j < 4; j++)
      acc[i][j] = (f32x4){0.f, 0.f, 0.f, 0.f};

  int r0 = t >> 2, kc = t & 3;
  int xorc = (kc ^ ((r0 >> 1) & 3)) * 8;              // (r0+64)>>1 & 3 == (r0>>1)&3
  const unsigned short* gA0 = Ab + (size_t)r0 * K + xorc;
  const unsigned short* gA1 = Ab + (size_t)(r0 + 64) * K + xorc;
  const unsigned short* gB0 = Bb + (size_t)r0 * K + xorc;
  const unsigned short* gB1 = Bb + (size_t)(r0 + 64) * K + xorc;
  int ls0 = w * 512;                                  // element offsets within a buffer
  int ls1 = 2048 + w * 512;

  int nt = K >> 5;
  unsigned short *A0 = lA, *A1 = lA + 4096, *A2 = lA + 8192;
  unsigned short *B0 = lB, *B1 = lB + 4096, *B2 = lB + 8192;

  // prologue: stage tile 0 -> buf0, tile 1 -> buf1 (8 loads outstanding)
  gload16(gA0, A0 + ls0); gload16(gA1, A0 + ls1);
  gload16(gB0, B0 + ls0); gload16(gB1, B0 + ls1);
  gload16(gA0 + 32, A1 + ls0); gload16(gA1 + 32, A1 + ls1);
  gload16(gB0 + 32, B1 + ls0); gload16(gB1 + 32, B1 + ls1);

  int colr = (lg ^ ((lr >> 1) & 3)) * 8;

  for (int tile = 0; tile < nt; ++tile) {
    if (tile + 2 < nt) {
      int k0 = (tile + 2) << 5;
      gload16(gA0 + k0, A2 + ls0); gload16(gA1 + k0, A2 + ls1);
      gload16(gB0 + k0, B2 + ls0); gload16(gB1 + k0, B2 + ls1);
      asm volatile("s_waitcnt vmcnt(8)" ::: "memory"); // tile `tile` landed; 2 in flight
    } else if (tile + 1 < nt) {
      asm volatile("s_waitcnt vmcnt(4)" ::: "memory");
    } else {
      asm volatile("s_waitcnt vmcnt(0)" ::: "memory");
    }
    __builtin_amdgcn_s_barrier();
    __builtin_amdgcn_sched_barrier(0);

    short8 af[4], bfr[4];
#pragma unroll
    for (int mi = 0; mi < 4; mi++)
      af[mi] = *(const short8*)(&A0[(wm + mi * 16 + lr) * 32 + colr]);
#pragma unroll
    for (int ni = 0; ni < 4; ni++)
      bfr[ni] = *(const short8*)(&B0[(wn + ni * 16 + lr) * 32 + colr]);
#pragma unroll
    for (int mi = 0; mi < 4; mi++)
#pragma unroll
      for (int ni = 0; ni < 4; ni++)
        acc[mi][ni] = __builtin_amdgcn_mfma_f32_16x16x32_bf16(af[mi], bfr[ni], acc[mi][ni], 0, 0, 0);

    __builtin_amdgcn_sched_barrier(0);
    __builtin_amdgcn_s_barrier();

    // rotate buffers (named pointers, no runtime-indexed arrays)
    unsigned short* tA = A0; A0 = A1; A1 = A2; A2 = tA;
    unsigned short* tB = B0; B0 = B1; B1 = B2; B2 = tB;
  }

  if (OUT_BF16) {
    size_t rbase = (size_t)mb * 128 + wm + lg * 4;
    size_t cbase = (size_t)nb * 128 + wn + lr;
    unsigned short* C = (unsigned short*)Cv + (size_t)b * M * SPATIAL;
#pragma unroll
    for (int mi = 0; mi < 4; mi++)
#pragma unroll
      for (int ni = 0; ni < 4; ni++) {
        size_t r = rbase + mi * 16;
        size_t c = cbase + ni * 16;
#pragma unroll
        for (int j = 0; j < 4; j++)
          C[(r + j) * SPATIAL + c] = f2bf(acc[mi][ni][j]);
      }
  } else {
    // LDS-bounce coalesced fp32 epilogue, two 64-row halves
    float* lC = (float*)smem;                         // [64][132] = 33792 B
    float* Cg = (float*)Cv + (size_t)b * M * SPATIAL;
#pragma unroll
    for (int half = 0; half < 2; ++half) {
      __syncthreads();
      if (wm == half * 64) {
#pragma unroll
        for (int mi = 0; mi < 4; mi++)
#pragma unroll
          for (int ni = 0; ni < 4; ni++) {
            int rl = mi * 16 + lg * 4;
            int c = wn + ni * 16 + lr;
#pragma unroll
            for (int j = 0; j < 4; j++)
              lC[(rl + j) * 132 + c] = acc[mi][ni][j];
          }
      }
      __syncthreads();
      int rl = t >> 2, c4 = (t & 3) * 4;
      size_t rg = (size_t)mb * 128 + half * 64 + rl;
#pragma unroll
      for (int i = 0; i < 8; i++) {
        f32x4 v = *(const f32x4*)(&lC[rl * 132 + i * 16 + c4]);
        *(f32x4*)(Cg + rg * SPATIAL + (size_t)nb * 128 + i * 16 + c4) = v;
      }
    }
  }
}

// ---------------- depthwise 3x3, vectorized: 8 x-pixels per thread ----------------
template<bool NORM>
__global__ __launch_bounds__(256)
void k_dwconv(const unsigned short* __restrict__ in, const float* __restrict__ wdw,
              unsigned short* __restrict__ out, float* __restrict__ norm2,
              int C, int in_cstride, int chan_off)
{
  int bid = blockIdx.x;
  int yt = bid & 7; bid >>= 3;                        // 8 y-tiles of 16 rows
  int c = bid % C; int b = bid / C;
  const unsigned short* ip = in + ((size_t)b * in_cstride + chan_off + c) * SPATIAL;
  const float* wp = wdw + (size_t)(chan_off + c) * 9;
  float wr[9];
#pragma unroll
  for (int i = 0; i < 9; i++) wr[i] = wp[i];

  int t = threadIdx.x;
  int ty = t >> 4, xs = (t & 15) * 8;
  int y = yt * 16 + ty;

  float acc[8];
#pragma unroll
  for (int j = 0; j < 8; j++) acc[j] = 0.f;

  auto row = [&](int yy, float wa, float wb, float wc) {
    if ((unsigned)yy >= 128u) return;
    const unsigned short* rp = ip + yy * 128 + xs;
    short8 cv = *(const short8*)rp;
    float cf[8];
#pragma unroll
    for (int j = 0; j < 8; j++) cf[j] = bf2f((unsigned short)cv[j]);
    float lf = (xs > 0) ? bf2f(rp[-1]) : 0.f;
    float rt = (xs < 120) ? bf2f(rp[8]) : 0.f;
    acc[0] += wa * lf + wb * cf[0] + wc * cf[1];
#pragma unroll
    for (int j = 1; j < 7; j++) acc[j] += wa * cf[j - 1] + wb * cf[j] + wc * cf[j + 1];
    acc[7] += wa * cf[6] + wb * cf[7] + wc * rt;
  };
  row(y - 1, wr[0], wr[1], wr[2]);
  row(y,     wr[3], wr[4], wr[5]);
  row(y + 1, wr[6], wr[7], wr[8]);

  short8 o;
  float sq = 0.f;
#pragma unroll
  for (int j = 0; j < 8; j++) {
    o[j] = (short)f2bf(acc[j]);
    if (NORM) { float v = bf2f((unsigned short)o[j]); sq += v * v; }
  }
  *(short8*)(out + ((size_t)b * C + c) * SPATIAL + y * 128 + xs) = o;

  if (NORM) {
#pragma unroll
    for (int off = 32; off > 0; off >>= 1) sq += __shfl_down(sq, off, 64);
    __shared__ float red[4];
    if ((t & 63) == 0) red[t >> 6] = sq;
    __syncthreads();
    if (t == 0)
      atomicAdd(&norm2[(size_t)b * C + c], red[0] + red[1] + red[2] + red[3]);
  }
}

// ---------------- depthwise 3x3 on v-half of qv, vectorized, transposed out vT [B][S][384] ----------------
__global__ __launch_bounds__(256)
void k_dwconv_t(const unsigned short* __restrict__ qv, const float* __restrict__ wdw,
                unsigned short* __restrict__ vT)
{
  __shared__ float tile[128][17];                     // [x][c-local]
  int bid = blockIdx.x;
  int y = bid & 127; bid >>= 7;
  int ct = bid % 24; int b = bid / 24;                // 24 tiles of 16 channels
  int t = threadIdx.x;
  int ci = t >> 4, xs = (t & 15) * 8;
  int c = CDIM + ct * 16 + ci;
  const unsigned short* ip = qv + ((size_t)b * QVDIM + c) * SPATIAL;
  const float* wp = wdw + (size_t)c * 9;
  float wr[9];
#pragma unroll
  for (int i = 0; i < 9; i++) wr[i] = wp[i];

  float acc[8];
#pragma unroll
  for (int j = 0; j < 8; j++) acc[j] = 0.f;

  auto row = [&](int yy, float wa, float wb, float wc) {
    if ((unsigned)yy >= 128u) return;
    const unsigned short* rp = ip + yy * 128 + xs;
    short8 cv = *(const short8*)rp;
    float cf[8];
#pragma unroll
    for (int j = 0; j < 8; j++) cf[j] = bf2f((unsigned short)cv[j]);
    float lf = (xs > 0) ? bf2f(rp[-1]) : 0.f;
    float rt = (xs < 120) ? bf2f(rp[8]) : 0.f;
    acc[0] += wa * lf + wb * cf[0] + wc * cf[1];
#pragma unroll
    for (int j = 1; j < 7; j++) acc[j] += wa * cf[j - 1] + wb * cf[j] + wc * cf[j + 1];
    acc[7] += wa * cf[6] + wb * cf[7] + wc * rt;
  };
  row(y - 1, wr[0], wr[1], wr[2]);
  row(y,     wr[3], wr[4], wr[5]);
  row(y + 1, wr[6], wr[7], wr[8]);

#pragma unroll
  for (int j = 0; j < 8; j++) tile[xs + j][ci] = acc[j];
  __syncthreads();

  int xw = t >> 1, cg = t & 1;
  short8 o;
#pragma unroll
  for (int j = 0; j < 8; j++) o[j] = (short)f2bf(tile[xw][cg * 8 + j]);
  *(short8*)(vT + ((size_t)b * SPATIAL + (size_t)y * 128 + xw) * CDIM + ct * 16 + cg * 8) = o;
}

// ---------------- raw attention logits: raw[b][h][c][d] += sum_s q[c,s]*k[d,s] ----------------
__global__ __launch_bounds__(256)
void k_logits(const unsigned short* __restrict__ qd, const unsigned short* __restrict__ kd,
              float* __restrict__ raw)
{
  int bid = blockIdx.x;
  int sp = bid & 15; bid >>= 4;
  int h = bid & 7; int b = bid >> 3;
  int lane = threadIdx.x & 63, wv = threadIdx.x >> 6;
  int lr = lane & 15, lg = lane >> 4;
  const unsigned short* qp = qd + ((size_t)b * CDIM + h * HC) * SPATIAL;
  const unsigned short* kp = kd + ((size_t)b * CDIM + h * HC) * SPATIAL;
  int s0 = sp * 1024 + wv * 256;
  f32x4 acc[3][3];
#pragma unroll
  for (int i = 0; i < 3; i++)
#pragma unroll
    for (int j = 0; j < 3; j++)
      acc[i][j] = (f32x4){0.f, 0.f, 0.f, 0.f};
  for (int ks = 0; ks < 256; ks += 32) {
    int off = s0 + ks + lg * 8;
    short8 qf[3], kf[3];
#pragma unroll
    for (int i = 0; i < 3; i++) {
      qf[i] = *(const short8*)(qp + (size_t)(i * 16 + lr) * SPATIAL + off);
      kf[i] = *(const short8*)(kp + (size_t)(i * 16 + lr) * SPATIAL + off);
    }
#pragma unroll
    for (int ci = 0; ci < 3; ci++)
#pragma unroll
      for (int di = 0; di < 3; di++)
        acc[ci][di] = __builtin_amdgcn_mfma_f32_16x16x32_bf16(qf[ci], kf[di], acc[ci][di], 0, 0, 0);
  }
  float* rp = raw + ((size_t)(b * NHEADS + h)) * HC * HC;
#pragma unroll
  for (int ci = 0; ci < 3; ci++)
#pragma unroll
    for (int di = 0; di < 3; di++)
#pragma unroll
      for (int j = 0; j < 4; j++)
        atomicAdd(&rp[(ci * 16 + lg * 4 + j) * HC + di * 16 + lr], acc[ci][di][j]);
}

// ---------------- scale by norms+temperature, softmax over d ----------------
__global__ void k_softmax(const float* __restrict__ raw, const float* __restrict__ n2q,
                          const float* __restrict__ n2k, const float* __restrict__ temp,
                          float* __restrict__ attn)
{
  int h = blockIdx.x & 7, b = blockIdx.x >> 3;
  int c = threadIdx.x;
  if (c >= HC) return;
  float tp = temp[h];
  float qn = fmaxf(sqrtf(n2q[b * CDIM + h * HC + c]), 1e-12f);
  const float* rp = raw + ((size_t)(b * NHEADS + h) * HC + c) * HC;
  float vals[HC];
  float mx = -1e30f;
#pragma unroll
  for (int d = 0; d < HC; d++) {
    float kn = fmaxf(sqrtf(n2k[b * CDIM + h * HC + d]), 1e-12f);
    float v = rp[d] * tp / (qn * kn);
    vals[d] = v;
    mx = fmaxf(mx, v);
  }
  float sum = 0.f;
#pragma unroll
  for (int d = 0; d < HC; d++) { vals[d] = expf(vals[d] - mx); sum += vals[d]; }
  float inv = 1.f / sum;
  float* ap = attn + ((size_t)(b * NHEADS + h) * HC + c) * HC;
#pragma unroll
  for (int d = 0; d < HC; d++) ap[d] = vals[d] * inv;
}

// ---------------- M[b][o][h*48+d] = sum_c wproj[o][h*48+c] * attn[b][h][c][d] ----------------
__global__ void k_mbuild(const float* __restrict__ attn, const float* __restrict__ wproj,
                         unsigned short* __restrict__ Mb)
{
  int o = blockIdx.x % CDIM, b = blockIdx.x / CDIM;
  int j = threadIdx.x;           // 0..383
  int h = j / HC, d = j % HC;
  const float* wp = wproj + (size_t)o * CDIM + h * HC;
  const float* ap = attn + (size_t)(b * NHEADS + h) * HC * HC + d;
  float s = 0.f;
#pragma unroll
  for (int cp = 0; cp < HC; cp++) s += wp[cp] * ap[cp * HC];
  Mb[((size_t)b * CDIM + o) * CDIM + j] = f2bf(s);
}

// ---------------- workspace layout (bytes) ----------------
static const size_t OFF_QV   = 0;            // qv bf16 [B][768][S]; later reused as k_dw
static const size_t OFF_KDW  = 0;            // alias: qv fully consumed before this is written
static const size_t OFF_XT   = 201326592;    // xT bf16 [B][S][384]; later q_dw [B][384][S]
static const size_t OFF_QDW  = 201326592;
static const size_t OFF_DET  = 301989888;    // deT bf16 [B][S][192]
static const size_t OFF_VT   = 301989888;    // vT bf16 [B][S][384] (alias over dead deT)
static const size_t OFF_KPRE = 402653184;    // k_pre bf16 [B][384][S]
static const size_t OFF_WQVB = 503316480;
static const size_t OFF_WKB  = 503906304;
static const size_t OFF_N2Q  = 504053760;
static const size_t OFF_N2K  = 504066048;
static const size_t OFF_RAW  = 504078336;
static const size_t OFF_ATTN = 504668160;
static const size_t OFF_MB   = 505257984;    // -> end ~484 MB

extern "C" void kernel_launch(void* const* d_in, const int* in_sizes, int n_in,
                              void* d_out, int out_size, void* d_ws, size_t ws_size,
                              hipStream_t stream) {
  const float* x      = (const float*)d_in[0];
  const float* de     = (const float*)d_in[1];
  const float* w_qv   = (const float*)d_in[2];
  const float* w_qvdw = (const float*)d_in[3];
  const float* w_k    = (const float*)d_in[4];
  const float* w_kdw  = (const float*)d_in[5];
  const float* w_proj = (const float*)d_in[6];
  const float* temp   = (const float*)d_in[7];

  char* ws = (char*)d_ws;
  unsigned short* qv    = (unsigned short*)(ws + OFF_QV);
  unsigned short* kdw   = (unsigned short*)(ws + OFF_KDW);
  unsigned short* xT    = (unsigned short*)(ws + OFF_XT);
  unsigned short* qdw   = (unsigned short*)(ws + OFF_QDW);
  unsigned short* deT   = (unsigned short*)(ws + OFF_DET);
  unsigned short* vT    = (unsigned short*)(ws + OFF_VT);
  unsigned short* kpre  = (unsigned short*)(ws + OFF_KPRE);
  unsigned short* wqvb  = (unsigned short*)(ws + OFF_WQVB);
  unsigned short* wkb   = (unsigned short*)(ws + OFF_WKB);
  float* n2q  = (float*)(ws + OFF_N2Q);
  float* n2k  = (float*)(ws + OFF_N2K);
  float* raw  = (float*)(ws + OFF_RAW);
  float* attn = (float*)(ws + OFF_ATTN);
  unsigned short* Mb = (unsigned short*)(ws + OFF_MB);

  hipMemsetAsync(ws + OFF_N2Q, 0, 12288 + 12288 + 589824, stream);

  k_w2bf<<<dim3((QVDIM * CDIM + 255) / 256), dim3(256), 0, stream>>>(w_qv, wqvb, QVDIM * CDIM);
  k_w2bf<<<dim3((CDIM * PDIM + 255) / 256), dim3(256), 0, stream>>>(w_k, wkb, CDIM * PDIM);

  k_transpose<<<dim3(BATCH * (CDIM / 64) * (SPATIAL / 64)), dim3(256), 0, stream>>>(x, xT, CDIM);
  k_transpose<<<dim3(BATCH * (PDIM / 64) * (SPATIAL / 64)), dim3(256), 0, stream>>>(de, deT, PDIM);

  // GEMM1: qv = w_qv @ x   (M=768, K=384); GEMM1b: k_pre = w_k @ de (M=384, K=192)
  k_gemm<true><<<dim3(BATCH * (QVDIM / 128) * (SPATIAL / 128)), dim3(256), 0, stream>>>(
      wqvb, xT, (void*)qv, QVDIM, CDIM, 0L);
  k_gemm<true><<<dim3(BATCH * (CDIM / 128) * (SPATIAL / 128)), dim3(256), 0, stream>>>(
      wkb, deT, (void*)kpre, CDIM, PDIM, 0L);

  // depthwise convs (vectorized, separate kernels — proven structure)
  k_dwconv<true><<<dim3(BATCH * CDIM * 8), dim3(256), 0, stream>>>(
      qv, w_qvdw, qdw, n2q, CDIM, QVDIM, 0);
  k_dwconv_t<<<dim3(BATCH * 24 * 128), dim3(256), 0, stream>>>(qv, w_qvdw, vT);
  k_dwconv<true><<<dim3(BATCH * CDIM * 8), dim3(256), 0, stream>>>(
      kpre, w_kdw, kdw, n2k, CDIM, CDIM, 0);

  // attention logits, softmax, combined projection matrix
  k_logits<<<dim3(BATCH * NHEADS * 16), dim3(256), 0, stream>>>(qdw, kdw, raw);
  k_softmax<<<dim3(BATCH * NHEADS), dim3(64), 0, stream>>>(raw, n2q, n2k, temp, attn);
  k_mbuild<<<dim3(BATCH * CDIM), dim3(CDIM), 0, stream>>>(attn, w_proj, Mb);

  // GEMM2: out = M[b] @ v  (M=384, K=384), fp32 output via coalesced LDS-bounce epilogue
  k_gemm<false><<<dim3(BATCH * (CDIM / 128) * (SPATIAL / 128)), dim3(256), 0, stream>>>(
      Mb, vT, d_out, CDIM, CDIM, (long)(CDIM * CDIM));
}

// Round 6
// 661.883 us; speedup vs baseline: 1.0698x; 1.0286x over previous
//
#include <hip/hip_runtime.h>

#define SPATIAL 16384
#define BATCH 8
#define CDIM 384
#define QVDIM 768
#define PDIM 192
#define NHEADS 8
#define HC 48

typedef __attribute__((ext_vector_type(8))) short short8;
typedef __attribute__((ext_vector_type(4))) float f32x4;
typedef __attribute__((ext_vector_type(4))) int i32x4;

__device__ __forceinline__ unsigned short f2bf(float f) {
  union { float f; unsigned u; } v; v.f = f;
  unsigned r = v.u + 0x7fffu + ((v.u >> 16) & 1u);
  return (unsigned short)(r >> 16);
}
__device__ __forceinline__ float bf2f(unsigned short h) {
  union { unsigned u; float f; } v; v.u = ((unsigned)h) << 16;
  return v.f;
}

// async global->LDS, 16B per lane; LDS dest is wave-uniform base + lane*16
__device__ __forceinline__ void gload16(const unsigned short* g, unsigned short* lds) {
  __builtin_amdgcn_global_load_lds(
      (const __attribute__((address_space(1))) void*)g,
      (__attribute__((address_space(3))) void*)lds,
      16, 0, 0);
}

// ---------------- weight fp32 -> bf16 ----------------
__global__ void k_w2bf(const float* __restrict__ in, unsigned short* __restrict__ out, int n) {
  int i = blockIdx.x * 256 + threadIdx.x;
  if (i < n) out[i] = f2bf(in[i]);
}

// ---------------- transpose fp32 [B][C][S] -> bf16 [B][S][C], 64x64 tiles ----------------
__global__ __launch_bounds__(256)
void k_transpose(const float* __restrict__ in, unsigned short* __restrict__ out, int C) {
  __shared__ float tile[64][65];
  int bid = blockIdx.x;
  int st = bid % (SPATIAL / 64); bid /= (SPATIAL / 64);
  int ct = bid % (C / 64); int b = bid / (C / 64);
  int t = threadIdx.x;
  const float* ip = in + ((size_t)b * C + (size_t)ct * 64) * SPATIAL + (size_t)st * 64;
  int fx = t & 15, fy = t >> 4;
#pragma unroll
  for (int i = 0; i < 4; i++) {
    int r = fy + i * 16;
    f32x4 v = *(const f32x4*)(ip + (size_t)r * SPATIAL + fx * 4);
    tile[r][fx * 4 + 0] = v[0];
    tile[r][fx * 4 + 1] = v[1];
    tile[r][fx * 4 + 2] = v[2];
    tile[r][fx * 4 + 3] = v[3];
  }
  __syncthreads();
  unsigned short* op = out + ((size_t)b * SPATIAL + (size_t)st * 64) * C + (size_t)ct * 64;
  int cg = t & 7, sr = t >> 3;
#pragma unroll
  for (int i = 0; i < 2; i++) {
    int s = sr + i * 32;
    short8 o;
#pragma unroll
    for (int j = 0; j < 8; j++) o[j] = (short)f2bf(tile[cg * 8 + j][s]);
    *(short8*)(op + (size_t)s * C + cg * 8) = o;
  }
}

// ---------------- GEMM: C[b][M][S] = A[M][K] @ B[b][S][K]^T ----------------
// 8-wave BN=256 step schedule: per K-step (BK=32) all fragment ds_reads are
// hoisted before a "reads-done" barrier, after which the current buffer is
// restaged with K-tile j+2 (2-K-tile lookahead, counted vmcnt never 0 in-loop).
// Same LDS swizzle/fragment addressing as the verified 128^2 kernel.
template<int BM, bool OUT_BF16>
__global__ __launch_bounds__(512, 2)
void k_gemm(const unsigned short* __restrict__ A, const unsigned short* __restrict__ B,
            void* __restrict__ Cv, int M, int K, long strideA)
{
  constexpr int MFR = BM / 32;          // m-frags per wave (8 or 4)
  constexpr int AR  = BM / 128;         // A staging rounds (2 or 1)
  constexpr int SL  = AR + 2;           // stage loads per thread per K-tile
  constexpr int ASZ = BM * 32;          // A-tile elems
  constexpr int BUF = ASZ + 256 * 32;   // elems per buffer

  int nwg = gridDim.x;                  // 1536, % 8 == 0
  int bid = (blockIdx.x & 7) * (nwg >> 3) + (blockIdx.x >> 3);
  int mt = M / BM;
  int mb = bid % mt; bid /= mt;
  int nb = bid & 63; int b = bid >> 6;

  const unsigned short* Ab = A + (size_t)b * strideA + (size_t)mb * BM * K;
  const unsigned short* Bb = B + ((size_t)b * SPATIAL + (size_t)nb * 256) * K;

  __shared__ unsigned short lds[2 * BUF];

  int t = threadIdx.x;
  int lane = t & 63;
  int w = t >> 6;
  int wm = (w >> 2) * (BM / 2), wn = (w & 3) * 64;
  int lr = lane & 15, lg = lane >> 4;
  int colr = (lg ^ ((lr >> 1) & 3)) * 8;

  f32x4 acc[MFR][4];
#pragma unroll
  for (int i = 0; i < MFR; i++)
#pragma unroll
    for (int j = 0; j < 4; j++)
      acc[i][j] = (f32x4){0.f, 0.f, 0.f, 0.f};

  // staging: chunk c = r2*512 + t -> row c>>2, kcol (c&3)^((row>>1)&3)
  int arow0 = t >> 2;
  int aslot = (t & 3) ^ ((arow0 >> 1) & 3);
  const unsigned short* gA0 = Ab + (size_t)arow0 * K + aslot * 8;
  const unsigned short* gB0 = Bb + (size_t)arow0 * K + aslot * 8;

  auto STAGE = [&](int kt, int q) {
    int k0 = kt * 32;
    unsigned short* base = &lds[q * BUF];
#pragma unroll
    for (int r2 = 0; r2 < AR; ++r2)
      gload16(gA0 + (size_t)r2 * 128 * K + k0, base + r2 * 4096 + w * 512);
#pragma unroll
    for (int r2 = 0; r2 < 2; ++r2)
      gload16(gB0 + (size_t)r2 * 128 * K + k0, base + ASZ + r2 * 4096 + w * 512);
  };

  int nt = K >> 5;
  STAGE(0, 0);
  STAGE(1, 1);
  asm volatile("s_waitcnt vmcnt(%0)" :: "n"(SL) : "memory");   // K0 landed, K1 in flight
  __builtin_amdgcn_sched_barrier(0);

  for (int j = 0; j < nt; ++j) {
    unsigned short* cb = &lds[(j & 1) * BUF];
    __builtin_amdgcn_s_barrier();            // (a) publish: this K-tile is in LDS
    __builtin_amdgcn_sched_barrier(0);

    short8 af[MFR], bfv[4];
#pragma unroll
    for (int mi = 0; mi < MFR; ++mi)
      af[mi] = *(const short8*)(&cb[(wm + mi * 16 + lr) * 32 + colr]);
#pragma unroll
    for (int ni = 0; ni < 4; ++ni)
      bfv[ni] = *(const short8*)(&cb[ASZ + (wn + ni * 16 + lr) * 32 + colr]);

    asm volatile("s_waitcnt lgkmcnt(0)" ::: "memory");
    __builtin_amdgcn_sched_barrier(0);
    __builtin_amdgcn_s_barrier();            // (b) all reads done: buffer free
    if (j + 2 < nt) STAGE(j + 2, j & 1);

    __builtin_amdgcn_s_setprio(1);
#pragma unroll
    for (int mi = 0; mi < MFR; ++mi)
#pragma unroll
      for (int ni = 0; ni < 4; ++ni)
        acc[mi][ni] = __builtin_amdgcn_mfma_f32_16x16x32_bf16(af[mi], bfv[ni], acc[mi][ni], 0, 0, 0);
    __builtin_amdgcn_s_setprio(0);
    __builtin_amdgcn_sched_barrier(0);

    if (j + 2 < nt) {
      asm volatile("s_waitcnt vmcnt(%0)" :: "n"(SL) : "memory");  // K-tile j+1 landed
    } else if (j + 1 < nt) {
      asm volatile("s_waitcnt vmcnt(0)" ::: "memory");
    }
    __builtin_amdgcn_sched_barrier(0);
  }

  size_t rbase = (size_t)mb * BM + wm + lg * 4;
  size_t cbase = (size_t)nb * 256 + wn + lr;
  if (OUT_BF16) {
    unsigned short* C = (unsigned short*)Cv + (size_t)b * M * SPATIAL;
#pragma unroll
    for (int mi = 0; mi < MFR; ++mi)
#pragma unroll
      for (int ni = 0; ni < 4; ++ni) {
        size_t r = rbase + mi * 16;
        size_t c = cbase + ni * 16;
#pragma unroll
        for (int jj = 0; jj < 4; ++jj)
          C[(r + jj) * SPATIAL + c] = f2bf(acc[mi][ni][jj]);
      }
  } else {
    float* C = (float*)Cv + (size_t)b * M * SPATIAL;
#pragma unroll
    for (int mi = 0; mi < MFR; ++mi)
#pragma unroll
      for (int ni = 0; ni < 4; ++ni) {
        size_t r = rbase + mi * 16;
        size_t c = cbase + ni * 16;
#pragma unroll
        for (int jj = 0; jj < 4; ++jj)
          C[(r + jj) * SPATIAL + c] = acc[mi][ni][jj];
      }
  }
}

// ---------------- depthwise 3x3, vectorized: 8 x-pixels per thread ----------------
template<bool NORM>
__global__ __launch_bounds__(256)
void k_dwconv(const unsigned short* __restrict__ in, const float* __restrict__ wdw,
              unsigned short* __restrict__ out, float* __restrict__ norm2,
              int C, int in_cstride, int chan_off)
{
  int bid = blockIdx.x;
  int yt = bid & 7; bid >>= 3;                        // 8 y-tiles of 16 rows
  int c = bid % C; int b = bid / C;
  const unsigned short* ip = in + ((size_t)b * in_cstride + chan_off + c) * SPATIAL;
  const float* wp = wdw + (size_t)(chan_off + c) * 9;
  float wr[9];
#pragma unroll
  for (int i = 0; i < 9; i++) wr[i] = wp[i];

  int t = threadIdx.x;
  int ty = t >> 4, xs = (t & 15) * 8;
  int y = yt * 16 + ty;

  float acc[8];
#pragma unroll
  for (int j = 0; j < 8; j++) acc[j] = 0.f;

  auto row = [&](int yy, float wa, float wb, float wc) {
    if ((unsigned)yy >= 128u) return;
    const unsigned short* rp = ip + yy * 128 + xs;
    short8 cv = *(const short8*)rp;
    float cf[8];
#pragma unroll
    for (int j = 0; j < 8; j++) cf[j] = bf2f((unsigned short)cv[j]);
    float lf = (xs > 0) ? bf2f(rp[-1]) : 0.f;
    float rt = (xs < 120) ? bf2f(rp[8]) : 0.f;
    acc[0] += wa * lf + wb * cf[0] + wc * cf[1];
#pragma unroll
    for (int j = 1; j < 7; j++) acc[j] += wa * cf[j - 1] + wb * cf[j] + wc * cf[j + 1];
    acc[7] += wa * cf[6] + wb * cf[7] + wc * rt;
  };
  row(y - 1, wr[0], wr[1], wr[2]);
  row(y,     wr[3], wr[4], wr[5]);
  row(y + 1, wr[6], wr[7], wr[8]);

  short8 o;
  float sq = 0.f;
#pragma unroll
  for (int j = 0; j < 8; j++) {
    o[j] = (short)f2bf(acc[j]);
    if (NORM) { float v = bf2f((unsigned short)o[j]); sq += v * v; }
  }
  *(short8*)(out + ((size_t)b * C + c) * SPATIAL + y * 128 + xs) = o;

  if (NORM) {
#pragma unroll
    for (int off = 32; off > 0; off >>= 1) sq += __shfl_down(sq, off, 64);
    __shared__ float red[4];
    if ((t & 63) == 0) red[t >> 6] = sq;
    __syncthreads();
    if (t == 0)
      atomicAdd(&norm2[(size_t)b * C + c], red[0] + red[1] + red[2] + red[3]);
  }
}

// ---------------- depthwise 3x3 on v-half of qv, vectorized, transposed out vT [B][S][384] ----------------
__global__ __launch_bounds__(256)
void k_dwconv_t(const unsigned short* __restrict__ qv, const float* __restrict__ wdw,
                unsigned short* __restrict__ vT)
{
  __shared__ float tile[128][17];                     // [x][c-local]
  int bid = blockIdx.x;
  int y = bid & 127; bid >>= 7;
  int ct = bid % 24; int b = bid / 24;                // 24 tiles of 16 channels
  int t = threadIdx.x;
  int ci = t >> 4, xs = (t & 15) * 8;
  int c = CDIM + ct * 16 + ci;
  const unsigned short* ip = qv + ((size_t)b * QVDIM + c) * SPATIAL;
  const float* wp = wdw + (size_t)c * 9;
  float wr[9];
#pragma unroll
  for (int i = 0; i < 9; i++) wr[i] = wp[i];

  float acc[8];
#pragma unroll
  for (int j = 0; j < 8; j++) acc[j] = 0.f;

  auto row = [&](int yy, float wa, float wb, float wc) {
    if ((unsigned)yy >= 128u) return;
    const unsigned short* rp = ip + yy * 128 + xs;
    short8 cv = *(const short8*)rp;
    float cf[8];
#pragma unroll
    for (int j = 0; j < 8; j++) cf[j] = bf2f((unsigned short)cv[j]);
    float lf = (xs > 0) ? bf2f(rp[-1]) : 0.f;
    float rt = (xs < 120) ? bf2f(rp[8]) : 0.f;
    acc[0] += wa * lf + wb * cf[0] + wc * cf[1];
#pragma unroll
    for (int j = 1; j < 7; j++) acc[j] += wa * cf[j - 1] + wb * cf[j] + wc * cf[j + 1];
    acc[7] += wa * cf[6] + wb * cf[7] + wc * rt;
  };
  row(y - 1, wr[0], wr[1], wr[2]);
  row(y,     wr[3], wr[4], wr[5]);
  row(y + 1, wr[6], wr[7], wr[8]);

#pragma unroll
  for (int j = 0; j < 8; j++) tile[xs + j][ci] = acc[j];
  __syncthreads();

  int xw = t >> 1, cg = t & 1;
  short8 o;
#pragma unroll
  for (int j = 0; j < 8; j++) o[j] = (short)f2bf(tile[xw][cg * 8 + j]);
  *(short8*)(vT + ((size_t)b * SPATIAL + (size_t)y * 128 + xw) * CDIM + ct * 16 + cg * 8) = o;
}

// ---------------- raw attention logits: raw[b][h][c][d] += sum_s q[c,s]*k[d,s] ----------------
__global__ __launch_bounds__(256)
void k_logits(const unsigned short* __restrict__ qd, const unsigned short* __restrict__ kd,
              float* __restrict__ raw)
{
  int bid = blockIdx.x;
  int sp = bid & 15; bid >>= 4;
  int h = bid & 7; int b = bid >> 3;
  int lane = threadIdx.x & 63, wv = threadIdx.x >> 6;
  int lr = lane & 15, lg = lane >> 4;
  const unsigned short* qp = qd + ((size_t)b * CDIM + h * HC) * SPATIAL;
  const unsigned short* kp = kd + ((size_t)b * CDIM + h * HC) * SPATIAL;
  int s0 = sp * 1024 + wv * 256;
  f32x4 acc[3][3];
#pragma unroll
  for (int i = 0; i < 3; i++)
#pragma unroll
    for (int j = 0; j < 3; j++)
      acc[i][j] = (f32x4){0.f, 0.f, 0.f, 0.f};
  for (int ks = 0; ks < 256; ks += 32) {
    int off = s0 + ks + lg * 8;
    short8 qf[3], kf[3];
#pragma unroll
    for (int i = 0; i < 3; i++) {
      qf[i] = *(const short8*)(qp + (size_t)(i * 16 + lr) * SPATIAL + off);
      kf[i] = *(const short8*)(kp + (size_t)(i * 16 + lr) * SPATIAL + off);
    }
#pragma unroll
    for (int ci = 0; ci < 3; ci++)
#pragma unroll
      for (int di = 0; di < 3; di++)
        acc[ci][di] = __builtin_amdgcn_mfma_f32_16x16x32_bf16(qf[ci], kf[di], acc[ci][di], 0, 0, 0);
  }
  float* rp = raw + ((size_t)(b * NHEADS + h)) * HC * HC;
#pragma unroll
  for (int ci = 0; ci < 3; ci++)
#pragma unroll
    for (int di = 0; di < 3; di++)
#pragma unroll
      for (int j = 0; j < 4; j++)
        atomicAdd(&rp[(ci * 16 + lg * 4 + j) * HC + di * 16 + lr], acc[ci][di][j]);
}

// ---------------- scale by norms+temperature, softmax over d ----------------
__global__ void k_softmax(const float* __restrict__ raw, const float* __restrict__ n2q,
                          const float* __restrict__ n2k, const float* __restrict__ temp,
                          float* __restrict__ attn)
{
  int h = blockIdx.x & 7, b = blockIdx.x >> 3;
  int c = threadIdx.x;
  if (c >= HC) return;
  float tp = temp[h];
  float qn = fmaxf(sqrtf(n2q[b * CDIM + h * HC + c]), 1e-12f);
  const float* rp = raw + ((size_t)(b * NHEADS + h) * HC + c) * HC;
  float vals[HC];
  float mx = -1e30f;
#pragma unroll
  for (int d = 0; d < HC; d++) {
    float kn = fmaxf(sqrtf(n2k[b * CDIM + h * HC + d]), 1e-12f);
    float v = rp[d] * tp / (qn * kn);
    vals[d] = v;
    mx = fmaxf(mx, v);
  }
  float sum = 0.f;
#pragma unroll
  for (int d = 0; d < HC; d++) { vals[d] = expf(vals[d] - mx); sum += vals[d]; }
  float inv = 1.f / sum;
  float* ap = attn + ((size_t)(b * NHEADS + h) * HC + c) * HC;
#pragma unroll
  for (int d = 0; d < HC; d++) ap[d] = vals[d] * inv;
}

// ---------------- M[b][o][h*48+d] = sum_c wproj[o][h*48+c] * attn[b][h][c][d] ----------------
__global__ void k_mbuild(const float* __restrict__ attn, const float* __restrict__ wproj,
                         unsigned short* __restrict__ Mb)
{
  int o = blockIdx.x % CDIM, b = blockIdx.x / CDIM;
  int j = threadIdx.x;           // 0..383
  int h = j / HC, d = j % HC;
  const float* wp = wproj + (size_t)o * CDIM + h * HC;
  const float* ap = attn + (size_t)(b * NHEADS + h) * HC * HC + d;
  float s = 0.f;
#pragma unroll
  for (int cp = 0; cp < HC; cp++) s += wp[cp] * ap[cp * HC];
  Mb[((size_t)b * CDIM + o) * CDIM + j] = f2bf(s);
}

// ---------------- workspace layout (bytes) ----------------
static const size_t OFF_QV   = 0;            // qv bf16 [B][768][S]; later reused as k_dw
static const size_t OFF_KDW  = 0;            // alias: qv fully consumed before this is written
static const size_t OFF_XT   = 201326592;    // xT bf16 [B][S][384]; later q_dw [B][384][S]
static const size_t OFF_QDW  = 201326592;
static const size_t OFF_DET  = 301989888;    // deT bf16 [B][S][192]
static const size_t OFF_VT   = 301989888;    // vT bf16 [B][S][384] (alias over dead deT)
static const size_t OFF_KPRE = 402653184;    // k_pre bf16 [B][384][S]
static const size_t OFF_WQVB = 503316480;
static const size_t OFF_WKB  = 503906304;
static const size_t OFF_N2Q  = 504053760;
static const size_t OFF_N2K  = 504066048;
static const size_t OFF_RAW  = 504078336;
static const size_t OFF_ATTN = 504668160;
static const size_t OFF_MB   = 505257984;    // -> end ~484 MB

extern "C" void kernel_launch(void* const* d_in, const int* in_sizes, int n_in,
                              void* d_out, int out_size, void* d_ws, size_t ws_size,
                              hipStream_t stream) {
  const float* x      = (const float*)d_in[0];
  const float* de     = (const float*)d_in[1];
  const float* w_qv   = (const float*)d_in[2];
  const float* w_qvdw = (const float*)d_in[3];
  const float* w_k    = (const float*)d_in[4];
  const float* w_kdw  = (const float*)d_in[5];
  const float* w_proj = (const float*)d_in[6];
  const float* temp   = (const float*)d_in[7];

  char* ws = (char*)d_ws;
  unsigned short* qv    = (unsigned short*)(ws + OFF_QV);
  unsigned short* kdw   = (unsigned short*)(ws + OFF_KDW);
  unsigned short* xT    = (unsigned short*)(ws + OFF_XT);
  unsigned short* qdw   = (unsigned short*)(ws + OFF_QDW);
  unsigned short* deT   = (unsigned short*)(ws + OFF_DET);
  unsigned short* vT    = (unsigned short*)(ws + OFF_VT);
  unsigned short* kpre  = (unsigned short*)(ws + OFF_KPRE);
  unsigned short* wqvb  = (unsigned short*)(ws + OFF_WQVB);
  unsigned short* wkb   = (unsigned short*)(ws + OFF_WKB);
  float* n2q  = (float*)(ws + OFF_N2Q);
  float* n2k  = (float*)(ws + OFF_N2K);
  float* raw  = (float*)(ws + OFF_RAW);
  float* attn = (float*)(ws + OFF_ATTN);
  unsigned short* Mb = (unsigned short*)(ws + OFF_MB);

  hipMemsetAsync(ws + OFF_N2Q, 0, 12288 + 12288 + 589824, stream);

  k_w2bf<<<dim3((QVDIM * CDIM + 255) / 256), dim3(256), 0, stream>>>(w_qv, wqvb, QVDIM * CDIM);
  k_w2bf<<<dim3((CDIM * PDIM + 255) / 256), dim3(256), 0, stream>>>(w_k, wkb, CDIM * PDIM);

  k_transpose<<<dim3(BATCH * (CDIM / 64) * (SPATIAL / 64)), dim3(256), 0, stream>>>(x, xT, CDIM);
  k_transpose<<<dim3(BATCH * (PDIM / 64) * (SPATIAL / 64)), dim3(256), 0, stream>>>(de, deT, PDIM);

  // GEMM1: qv = w_qv @ x   (M=768, K=384, BM=256)
  k_gemm<256, true><<<dim3(BATCH * (QVDIM / 256) * (SPATIAL / 256)), dim3(512), 0, stream>>>(
      wqvb, xT, (void*)qv, QVDIM, CDIM, 0L);
  // GEMM1b: k_pre = w_k @ de (M=384, K=192, BM=128)
  k_gemm<128, true><<<dim3(BATCH * (CDIM / 128) * (SPATIAL / 256)), dim3(512), 0, stream>>>(
      wkb, deT, (void*)kpre, CDIM, PDIM, 0L);

  // depthwise convs (vectorized, separate kernels — proven structure)
  k_dwconv<true><<<dim3(BATCH * CDIM * 8), dim3(256), 0, stream>>>(
      qv, w_qvdw, qdw, n2q, CDIM, QVDIM, 0);
  k_dwconv_t<<<dim3(BATCH * 24 * 128), dim3(256), 0, stream>>>(qv, w_qvdw, vT);
  k_dwconv<true><<<dim3(BATCH * CDIM * 8), dim3(256), 0, stream>>>(
      kpre, w_kdw, kdw, n2k, CDIM, CDIM, 0);

  // attention logits, softmax, combined projection matrix
  k_logits<<<dim3(BATCH * NHEADS * 16), dim3(256), 0, stream>>>(qdw, kdw, raw);
  k_softmax<<<dim3(BATCH * NHEADS), dim3(64), 0, stream>>>(raw, n2q, n2k, temp, attn);
  k_mbuild<<<dim3(BATCH * CDIM), dim3(CDIM), 0, stream>>>(attn, w_proj, Mb);

  // GEMM2: out = M[b] @ v  (M=384, K=384, BM=128), fp32 output
  k_gemm<128, false><<<dim3(BATCH * (CDIM / 128) * (SPATIAL / 256)), dim3(512), 0, stream>>>(
      Mb, vT, d_out, CDIM, CDIM, (long)(CDIM * CDIM));
}